// Round 8
// baseline (267.112 us; speedup 1.0000x reference)
//
#include <hip/hip_runtime.h>
#include <hip/hip_bf16.h>
#include <cstdint>
#include <cstddef>

// Problem constants (DeepseekV3Experts: T=1024 H=1024 I=1408 E=8 K=4)
#define NE 8
#define NT 1024
#define NK 4
#define NH 1024
#define NI 1408
#define NA (NT * NK)      // 4096 assignments
#define BM 128            // row tile
#define MAXTILES 40
#define PADSLOTS 5120

typedef short short8 __attribute__((ext_vector_type(8)));
typedef float f32x4 __attribute__((ext_vector_type(4)));
typedef float f4v __attribute__((ext_vector_type(4)));
typedef unsigned short u16;

// Workspace layout (bytes).
#define WS_HDR   0
#define WS_SORT  1024
#define WS_XBF   21504      // u16[NT*NH]
#define WS_GT    2118656    // u16[NE*NI*NH]  gate^T; dead after k2 -> part[2] planes
#define WS_UT    25187328   // u16[NE*NI*NH]  up^T
#define WS_DT    48256000   // u16[NE*NH*NI]  down^T [E][H][I]
#define WS_HB    71324672   // u16[PADSLOTS*NI]
// slotOf[NA] in hbuf's guaranteed-unused tail (padded slots <= 4992 < 5120).
#define WS_SLOT  (WS_HB + 4992 * NI * 2)   // int[NA]
#define PART_PLANE (PADSLOTS * NH)         // floats per part plane

__device__ __forceinline__ u16 f2b(float f) {
  union { float f; uint32_t u; } c; c.f = f;
  uint32_t u = c.u;
  return (u16)((u + 0x7FFFu + ((u >> 16) & 1u)) >> 16);  // RNE
}

__device__ __forceinline__ void llds16(const void* g, void* l) {
  __builtin_amdgcn_global_load_lds(
      (const __attribute__((address_space(1))) void*)g,
      (__attribute__((address_space(3))) void*)l, 16, 0, 0);
}

// Depth-2 pipelined transpose-convert: TWO 64k x 128n stripes (k0a, k0a+64).
// All 16 nt-loads issued up front -> stripe-1's HBM latency hides under stripe-0's
// LDS/store phases (G15 async-split; k1 occupancy was 47% -> latency-exposed).
// LDS tile: stride 64 u16, XOR swizzle col' = col ^ (row & 56)
// (round-4 verified conflict-free: SQ_LDS_BANK_CONFLICT 7.57M -> 1.6K).
__device__ __forceinline__ void transcvt_pipe(const float* __restrict__ src,
                                              u16* __restrict__ dst,
                                              int K, int N, int k0a, int n0,
                                              u16* smem, int tid) {
  u16 (*t2)[64][64] = (u16(*)[64][64])smem;
  int r = tid >> 4, c = tid & 15;          // 16 x 16 over (row, col16)
  f4v v[2][2][4];
#pragma unroll
  for (int s2 = 0; s2 < 2; ++s2)
#pragma unroll
    for (int t = 0; t < 2; ++t)
#pragma unroll
      for (int i = 0; i < 4; ++i)
        v[s2][t][i] = __builtin_nontemporal_load(
            (const f4v*)&src[(size_t)(k0a + s2 * 64 + r + 16 * i) * N + n0 + t * 64 + c * 4]);
#pragma unroll
  for (int s2 = 0; s2 < 2; ++s2) {
    int k0 = k0a + s2 * 64;
    if (s2) __syncthreads();   // LDS reuse fence between stripes
#pragma unroll
    for (int t = 0; t < 2; ++t)
#pragma unroll
      for (int i = 0; i < 4; ++i) {
        ushort4 o;
        o.x = f2b(v[s2][t][i].x); o.y = f2b(v[s2][t][i].y);
        o.z = f2b(v[s2][t][i].z); o.w = f2b(v[s2][t][i].w);
        int row = r + 16 * i;
        int sc = (c * 4) ^ (row & 56);
        *(ushort4*)&t2[t][row][sc] = o;
      }
    __syncthreads();
#pragma unroll
    for (int t = 0; t < 2; ++t)
#pragma unroll
      for (int i = 0; i < 2; ++i) {
        int idx = i * 256 + tid;
        int n = idx >> 3, kc = idx & 7;
        int cs = n ^ (kc * 8);
        u16 o[8];
#pragma unroll
        for (int j = 0; j < 8; ++j) o[j] = t2[t][kc * 8 + j][cs];
        *(short8*)&dst[(size_t)(n0 + t * 64 + n) * K + k0 + kc * 8] = *(const short8*)o;
      }
  }
}

// ---------------- K1: all conversions + bucket ----------------
// Grid (88, 26): y<16 gate/up (nb = x%11, kb-pair = x/11, 8 pairs);
// y in 16..23 down (nb = x%8, kb-pair = x/8, 11 pairs); y==24 x convert; y==25 bucket.
__global__ __launch_bounds__(256) void k1_prep(
    const float* __restrict__ gw, const float* __restrict__ uw, const float* __restrict__ dw,
    const float* __restrict__ hs, const int* __restrict__ sel,
    u16* __restrict__ gT, u16* __restrict__ uT, u16* __restrict__ dT, u16* __restrict__ xbf,
    int* __restrict__ hdr, int* __restrict__ sorted, int* __restrict__ slotOf) {
  int tid = threadIdx.x;
  int y = blockIdx.y;
  if (y == 24) {  // hidden_states convert (1M elements)
    for (int i = blockIdx.x * 256 + tid; i * 4 < NT * NH; i += 88 * 256) {
      f4v v = __builtin_nontemporal_load((const f4v*)&hs[i * 4]);
      ushort4 o;
      o.x = f2b(v.x); o.y = f2b(v.y); o.z = f2b(v.z); o.w = f2b(v.w);
      *(ushort4*)&xbf[i * 4] = o;
    }
    return;
  }
  if (y == 25) {
    if (blockIdx.x != 0) return;
    // bucket (single block)
    __shared__ int cnt[NE], fill[NE], poff_s[NE + 1];
    if (tid < NE) { cnt[tid] = 0; fill[tid] = 0; }
    __syncthreads();
    for (int i = tid; i < NA; i += 256) atomicAdd(&cnt[sel[i]], 1);
    __syncthreads();
    if (tid == 0) {
      int off = 0, nt = 0;
      for (int e = 0; e < NE; ++e) {
        poff_s[e] = off;
        int tiles = (cnt[e] + BM - 1) / BM;
        for (int j = 0; j < tiles; ++j) { hdr[32 + nt] = e; hdr[80 + nt] = off + j * BM; ++nt; }
        off += tiles * BM;
      }
      poff_s[NE] = off;
      hdr[17] = nt;
      for (int e = 0; e < NE; ++e) hdr[e] = cnt[e];
      for (int e = 0; e <= NE; ++e) hdr[8 + e] = poff_s[e];
    }
    __syncthreads();
    for (int i = tid; i < PADSLOTS; i += 256) sorted[i] = -1;
    __syncthreads();
    for (int i = tid; i < NA; i += 256) {
      int e = sel[i];
      int p = atomicAdd(&fill[e], 1);
      int s = poff_s[e] + p;
      sorted[s] = i;
      slotOf[i] = s;
    }
    return;
  }
  __shared__ u16 smem[2 * 64 * 64];
  if (y < 16) {   // gate/up: K=NH (8 kb-pairs), N=NI (11 nb)
    int tensor = y >> 3, e = y & 7;
    const float* src = ((tensor == 0) ? gw : uw) + (size_t)e * NH * NI;
    u16* dst = ((tensor == 0) ? gT : uT) + (size_t)e * NH * NI;
    int nb = blockIdx.x % 11, kbp = blockIdx.x / 11;
    transcvt_pipe(src, dst, NH, NI, kbp * 128, nb * 128, smem, tid);
  } else {        // down: K=NI (11 kb-pairs), N=NH (8 nb)
    int e = y - 16;
    const float* src = dw + (size_t)e * NI * NH;
    u16* dst = dT + (size_t)e * NI * NH;
    int nb = blockIdx.x % 8, kbp = blockIdx.x / 8;
    transcvt_pipe(src, dst, NI, NH, kbp * 128, nb * 128, smem, tid);
  }
}

// ---------------- K2: gemm1, 128x128 tile, BK=32, 2-buf, 3 blocks/CU, XCD swizzle ----------
// TLP over ILP-depth (m114; r2/r3 k3 evidence): 2-buf 48 KB -> 3 blocks/CU (12 waves)
// vs prior 3-buf 72 KB / 2 blocks. Depth-1 prefetch: STAGE(t+1) issued right after the
// barrier, compute(t) overlaps its flight; vmcnt(0)+barrier once per K-step.
// Race audit: STAGE(t+1) writes buf (t+1)&1; last read of that buf = compute(t-1),
// which precedes barrier(t) for every wave.
__global__ __launch_bounds__(256, 3) void k2_gemm1(
    const u16* __restrict__ xbf, const u16* __restrict__ gT, const u16* __restrict__ uT,
    u16* __restrict__ hbuf, const int* __restrict__ hdr, const int* __restrict__ sorted) {
  __shared__ u16 smem[24576];   // 48 KB = 2 bufs x (A 8K | Bg 8K | Bu 8K bytes)
  int b = blockIdx.x;
  int tid = threadIdx.x;

  int job = (b & 7) * 55 + (b >> 3);   // bijective for 440 = 8*55 (XCD n-locality)
  int tile = job % 40;
  if (tile >= hdr[17]) return;
  int e = hdr[32 + tile];
  int slot0 = hdr[80 + tile];
  int n0 = (job / 40) * 128;

  const u16* aptr[2];
  const u16 *bgp[2], *bup[2];
#pragma unroll
  for (int s = 0; s < 2; ++s) {
    int idx = s * 256 + tid;
    int row = idx >> 2, c = idx & 3;
    int kc = c ^ (row & 3) ^ ((row >> 2) & 3);
    int as = sorted[slot0 + row];
    int trow = (as >= 0) ? (as >> 2) : 0;
    aptr[s] = xbf + (size_t)trow * NH + kc * 8;
    size_t o = ((size_t)e * NI + n0 + row) * NH + kc * 8;
    bgp[s] = gT + o; bup[s] = uT + o;
  }

  int lane = tid & 63, wave = tid >> 6;
  int wm = wave >> 1, wn = wave & 1;
  int l15 = lane & 15, quad = lane >> 4;
  int pos = ((quad ^ (l15 & 3) ^ ((l15 >> 2) & 3)) & 3) * 8;

  f32x4 accg[4][4] = {}; f32x4 accu[4][4] = {};

#define K2_STAGE(BUF, KT)                                                \
  {                                                                      \
    int ko_ = (KT) * 32;                                                 \
    u16* p_ = smem + (BUF) * 12288;                                      \
    llds16(aptr[0] + ko_, p_ + tid * 8);                                 \
    llds16(aptr[1] + ko_, p_ + (256 + tid) * 8);                         \
    llds16(bgp[0] + ko_, p_ + 4096 + tid * 8);                           \
    llds16(bgp[1] + ko_, p_ + 4096 + (256 + tid) * 8);                   \
    llds16(bup[0] + ko_, p_ + 8192 + tid * 8);                           \
    llds16(bup[1] + ko_, p_ + 8192 + (256 + tid) * 8);                   \
  }

  K2_STAGE(0, 0);
  for (int kt = 0; kt < 32; ++kt) {
    asm volatile("s_waitcnt vmcnt(0)" ::: "memory");   // tile kt's 6 loads landed
    __builtin_amdgcn_s_barrier();
    __builtin_amdgcn_sched_barrier(0);
    if (kt < 31) K2_STAGE((kt + 1) & 1, kt + 1);       // in flight under compute(kt)
    const u16* sA  = smem + (kt & 1) * 12288;
    const u16* sBg = sA + 4096;
    const u16* sBu = sA + 8192;
    short8 av[4], bg[4], bu[4];
#pragma unroll
    for (int mf = 0; mf < 4; ++mf)
      av[mf] = *(const short8*)&sA[(wm * 64 + mf * 16 + l15) * 32 + pos];
#pragma unroll
    for (int nf = 0; nf < 4; ++nf) {
      bg[nf] = *(const short8*)&sBg[(wn * 64 + nf * 16 + l15) * 32 + pos];
      bu[nf] = *(const short8*)&sBu[(wn * 64 + nf * 16 + l15) * 32 + pos];
    }
#pragma unroll
    for (int mf = 0; mf < 4; ++mf)
#pragma unroll
      for (int nf = 0; nf < 4; ++nf) {
        accg[mf][nf] = __builtin_amdgcn_mfma_f32_16x16x32_bf16(av[mf], bg[nf], accg[mf][nf], 0, 0, 0);
        accu[mf][nf] = __builtin_amdgcn_mfma_f32_16x16x32_bf16(av[mf], bu[nf], accu[mf][nf], 0, 0, 0);
      }
  }
#undef K2_STAGE

  for (int mf = 0; mf < 4; ++mf)
    for (int nf = 0; nf < 4; ++nf)
      for (int r = 0; r < 4; ++r) {
        int row = wm * 64 + mf * 16 + quad * 4 + r;
        int col = n0 + wn * 64 + nf * 16 + l15;
        float g2 = accg[mf][nf][r], u = accu[mf][nf][r];
        float hv = (g2 / (1.f + __expf(-g2))) * u;
        hbuf[(size_t)(slot0 + row) * NI + col] = f2b(hv);
      }
}

// ---------------- K3: down proj 128x128, BK=32, K-SPLIT-2, XCD-sliced, NO atomics ----------
// (unchanged from round 7: 640 blocks, 3-buf 48 KB, vmcnt(4), part planes)
__global__ __launch_bounds__(256, 3) void k3_gemm2(
    const u16* __restrict__ hbuf, const u16* __restrict__ dT,
    const float* __restrict__ rw, float* __restrict__ part,
    const int* __restrict__ hdr, const int* __restrict__ sorted) {
  __shared__ u16 smem[24576];   // 48 KB
  int b = blockIdx.x;
  int nsl = b & 7;
  int r = b >> 3;
  int tile = r % 40;
  int kh = r / 40;              // 0/1: K-steps [0,22) / [22,44)
  if (tile >= hdr[17]) return;
  int e = hdr[32 + tile];
  int slot0 = hdr[80 + tile];
  int n0 = nsl * 128;
  int tid = threadIdx.x;

  const u16 *ap[2], *bp[2];
#pragma unroll
  for (int s = 0; s < 2; ++s) {
    int idx = s * 256 + tid;
    int row = idx >> 2, c = idx & 3;
    int kc = c ^ (row & 3) ^ ((row >> 2) & 3);
    ap[s] = hbuf + (size_t)(slot0 + row) * NI + kc * 8;
    bp[s] = dT + ((size_t)e * NH + n0 + row) * NI + kc * 8;
  }

  int lane = tid & 63, wave = tid >> 6;
  int wm = wave >> 1, wn = wave & 1;
  int l15 = lane & 15, quad = lane >> 4;
  int pos = ((quad ^ (l15 & 3) ^ ((l15 >> 2) & 3)) & 3) * 8;

  f32x4 acc[4][4] = {};

#define K3_STAGE(BUF, KT)                                                \
  {                                                                      \
    int ko_ = (KT) * 32;                                                 \
    u16* p_ = smem + (BUF) * 8192;                                       \
    llds16(ap[0] + ko_, p_ + tid * 8);                                   \
    llds16(ap[1] + ko_, p_ + (256 + tid) * 8);                           \
    llds16(bp[0] + ko_, p_ + 4096 + tid * 8);                            \
    llds16(bp[1] + ko_, p_ + 4096 + (256 + tid) * 8);                    \
  }

  int kt0 = kh * 22;
  K3_STAGE(0, kt0);
  K3_STAGE(1, kt0 + 1);
  for (int kt = 0; kt < 22; ++kt) {
    if (kt == 21) { asm volatile("s_waitcnt vmcnt(0)" ::: "memory"); }
    else          { asm volatile("s_waitcnt vmcnt(4)" ::: "memory"); }
    __builtin_amdgcn_s_barrier();
    __builtin_amdgcn_sched_barrier(0);
    if (kt < 20) K3_STAGE((kt + 2) % 3, kt0 + kt + 2);
    const u16* sA = smem + (kt % 3) * 8192;
    const u16* sB = sA + 4096;
    short8 av[4], bv[4];
#pragma unroll
    for (int mf = 0; mf < 4; ++mf)
      av[mf] = *(const short8*)&sA[(wm * 64 + mf * 16 + l15) * 32 + pos];
#pragma unroll
    for (int nf = 0; nf < 4; ++nf)
      bv[nf] = *(const short8*)&sB[(wn * 64 + nf * 16 + l15) * 32 + pos];
#pragma unroll
    for (int mf = 0; mf < 4; ++mf)
#pragma unroll
      for (int nf = 0; nf < 4; ++nf)
        acc[mf][nf] = __builtin_amdgcn_mfma_f32_16x16x32_bf16(av[mf], bv[nf], acc[mf][nf], 0, 0, 0);
  }
#undef K3_STAGE

  // weighted partial store into this K-half's plane (no collisions)
  float* plane = part + (size_t)kh * PART_PLANE;
  for (int mf = 0; mf < 4; ++mf) {
    int rowb = wm * 64 + mf * 16 + quad * 4;
    for (int rr = 0; rr < 4; ++rr) {
      int slot = slot0 + rowb + rr;
      int as = sorted[slot];
      if (as < 0) continue;
      float w = rw[as];
      float* prow = plane + (size_t)slot * NH + n0 + wn * 64;
      for (int nf = 0; nf < 4; ++nf)
        prow[nf * 16 + l15] = w * acc[mf][nf][rr];
    }
  }
}

// ---------------- K4: per-token combine: out[t] = sum_{k,kh} part[kh][slotOf[4t+k]] --------
__global__ __launch_bounds__(256) void k4_combine(
    const float* __restrict__ part, const int* __restrict__ slotOf,
    float* __restrict__ out) {
  int tid = threadIdx.x;
  int token = blockIdx.x * 2 + (tid >> 7);
  int col0 = (tid & 127) * 8;
  const int* sl = slotOf + token * 4;
  f4v a0 = {0.f, 0.f, 0.f, 0.f}, a1 = {0.f, 0.f, 0.f, 0.f};
#pragma unroll
  for (int k = 0; k < 4; ++k) {
    size_t ro = (size_t)sl[k] * NH + col0;
    const float* p0 = part + ro;
    const float* p1 = part + (size_t)PART_PLANE + ro;
    a0 += *(const f4v*)p0;
    a1 += *(const f4v*)(p0 + 4);
    a0 += *(const f4v*)p1;
    a1 += *(const f4v*)(p1 + 4);
  }
  float* o = out + (size_t)token * NH + col0;
  *(f4v*)o = a0;
  *(f4v*)(o + 4) = a1;
}

extern "C" void kernel_launch(void* const* d_in, const int* in_sizes, int n_in,
                              void* d_out, int out_size, void* d_ws, size_t ws_size,
                              hipStream_t stream) {
  const float* hs  = (const float*)d_in[0];
  const float* rw  = (const float*)d_in[1];
  const float* gw  = (const float*)d_in[2];
  const float* uw  = (const float*)d_in[3];
  const float* dw  = (const float*)d_in[4];
  const int*   sel = (const int*)d_in[5];
  float* out = (float*)d_out;

  char* ws = (char*)d_ws;
  int*  hdr    = (int*)(ws + WS_HDR);
  int*  sorted = (int*)(ws + WS_SORT);
  u16*  xbf    = (u16*)(ws + WS_XBF);
  u16*  gT     = (u16*)(ws + WS_GT);
  u16*  uT     = (u16*)(ws + WS_UT);
  u16*  dT     = (u16*)(ws + WS_DT);
  u16*  hb     = (u16*)(ws + WS_HB);
  float* part  = (float*)(ws + WS_GT);    // 2 planes x 21 MB in gT+uT region (dead after k2)
  int*  slotOf = (int*)(ws + WS_SLOT);    // hbuf tail rows [4992,5120)

  hipLaunchKernelGGL(k1_prep, dim3(88, 26), dim3(256), 0, stream,
                     gw, uw, dw, hs, sel, gT, uT, dT, xbf, hdr, sorted, slotOf);
  hipLaunchKernelGGL(k2_gemm1, dim3(440), dim3(256), 0, stream,
                     xbf, gT, uT, hb, hdr, sorted);
  hipLaunchKernelGGL(k3_gemm2, dim3(640), dim3(256), 0, stream,
                     hb, dT, rw, part, hdr, sorted);
  hipLaunchKernelGGL(k4_combine, dim3(512), dim3(256), 0, stream,
                     part, slotOf, out);
}

// Round 9
// 236.836 us; speedup vs baseline: 1.1278x; 1.1278x over previous
//
#include <hip/hip_runtime.h>
#include <hip/hip_bf16.h>
#include <cstdint>
#include <cstddef>

// Problem constants (DeepseekV3Experts: T=1024 H=1024 I=1408 E=8 K=4)
#define NE 8
#define NT 1024
#define NK 4
#define NH 1024
#define NI 1408
#define NA (NT * NK)      // 4096 assignments
#define BM 128            // row tile
#define MAXTILES 40
#define PADSLOTS 5120

typedef short short8 __attribute__((ext_vector_type(8)));
typedef float f32x4 __attribute__((ext_vector_type(4)));
typedef float f4v __attribute__((ext_vector_type(4)));
typedef unsigned short u16;

// Workspace layout (bytes).
#define WS_HDR   0
#define WS_SORT  1024
#define WS_XBF   21504      // u16[NT*NH]
#define WS_GT    2118656    // u16[NE*NI*NH]  gate^T; dead after k2 -> part[2] planes
#define WS_UT    25187328   // u16[NE*NI*NH]  up^T
#define WS_DT    48256000   // u16[NE*NH*NI]  down^T [E][H][I]
#define WS_HB    71324672   // u16[PADSLOTS*NI]
// slotOf[NA] in hbuf's guaranteed-unused tail (padded slots <= 4992 < 5120).
#define WS_SLOT  (WS_HB + 4992 * NI * 2)   // int[NA]
#define PART_PLANE (PADSLOTS * NH)         // floats per part plane

__device__ __forceinline__ u16 f2b(float f) {
  union { float f; uint32_t u; } c; c.f = f;
  uint32_t u = c.u;
  return (u16)((u + 0x7FFFu + ((u >> 16) & 1u)) >> 16);  // RNE
}

__device__ __forceinline__ void llds16(const void* g, void* l) {
  __builtin_amdgcn_global_load_lds(
      (const __attribute__((address_space(1))) void*)g,
      (__attribute__((address_space(3))) void*)l, 16, 0, 0);
}

// Shared transpose-convert stripe: [K][N] fp32 -> [N][K] bf16, 64k x 128n per block.
// LDS tile: stride 64 u16 (128 B) with XOR swizzle col' = col ^ (row & 56).
// (round-4 verified conflict-free: SQ_LDS_BANK_CONFLICT 7.57M -> 1.6K)
__device__ __forceinline__ void transcvt_stripe(const float* __restrict__ src,
                                                u16* __restrict__ dst,
                                                int K, int N, int k0, int n0,
                                                u16* smem, int tid) {
  u16 (*t2)[64][64] = (u16(*)[64][64])smem;
  int r = tid >> 4, c = tid & 15;          // 16 x 16 over (row, col16)
  f4v v[2][4];
#pragma unroll
  for (int t = 0; t < 2; ++t)
#pragma unroll
    for (int i = 0; i < 4; ++i)
      v[t][i] = __builtin_nontemporal_load(
          (const f4v*)&src[(size_t)(k0 + r + 16 * i) * N + n0 + t * 64 + c * 4]);
#pragma unroll
  for (int t = 0; t < 2; ++t)
#pragma unroll
    for (int i = 0; i < 4; ++i) {
      ushort4 o;
      o.x = f2b(v[t][i].x); o.y = f2b(v[t][i].y); o.z = f2b(v[t][i].z); o.w = f2b(v[t][i].w);
      int row = r + 16 * i;
      int sc = (c * 4) ^ (row & 56);
      *(ushort4*)&t2[t][row][sc] = o;
    }
  __syncthreads();
#pragma unroll
  for (int t = 0; t < 2; ++t)
#pragma unroll
    for (int i = 0; i < 2; ++i) {
      int idx = i * 256 + tid;
      int n = idx >> 3, kc = idx & 7;
      int cs = n ^ (kc * 8);
      u16 o[8];
#pragma unroll
      for (int j = 0; j < 8; ++j) o[j] = t2[t][kc * 8 + j][cs];
      *(short8*)&dst[(size_t)(n0 + t * 64 + n) * K + k0 + kc * 8] = *(const short8*)o;
    }
}

// ---------------- K1: all conversions + bucket (round-7 proven version) ----------------
__global__ __launch_bounds__(256) void k1_prep(
    const float* __restrict__ gw, const float* __restrict__ uw, const float* __restrict__ dw,
    const float* __restrict__ hs, const int* __restrict__ sel,
    u16* __restrict__ gT, u16* __restrict__ uT, u16* __restrict__ dT, u16* __restrict__ xbf,
    int* __restrict__ hdr, int* __restrict__ sorted, int* __restrict__ slotOf) {
  int tid = threadIdx.x;
  int y = blockIdx.y;
  if (y == 24) {  // hidden_states convert (1M elements)
    for (int i = blockIdx.x * 256 + tid; i * 4 < NT * NH; i += 176 * 256) {
      f4v v = __builtin_nontemporal_load((const f4v*)&hs[i * 4]);
      ushort4 o;
      o.x = f2b(v.x); o.y = f2b(v.y); o.z = f2b(v.z); o.w = f2b(v.w);
      *(ushort4*)&xbf[i * 4] = o;
    }
    return;
  }
  if (y == 25) {
    if (blockIdx.x != 0) return;
    // bucket (single block)
    __shared__ int cnt[NE], fill[NE], poff_s[NE + 1];
    if (tid < NE) { cnt[tid] = 0; fill[tid] = 0; }
    __syncthreads();
    for (int i = tid; i < NA; i += 256) atomicAdd(&cnt[sel[i]], 1);
    __syncthreads();
    if (tid == 0) {
      int off = 0, nt = 0;
      for (int e = 0; e < NE; ++e) {
        poff_s[e] = off;
        int tiles = (cnt[e] + BM - 1) / BM;
        for (int j = 0; j < tiles; ++j) { hdr[32 + nt] = e; hdr[80 + nt] = off + j * BM; ++nt; }
        off += tiles * BM;
      }
      poff_s[NE] = off;
      hdr[17] = nt;
      for (int e = 0; e < NE; ++e) hdr[e] = cnt[e];
      for (int e = 0; e <= NE; ++e) hdr[8 + e] = poff_s[e];
    }
    __syncthreads();
    for (int i = tid; i < PADSLOTS; i += 256) sorted[i] = -1;
    __syncthreads();
    for (int i = tid; i < NA; i += 256) {
      int e = sel[i];
      int p = atomicAdd(&fill[e], 1);
      int s = poff_s[e] + p;
      sorted[s] = i;
      slotOf[i] = s;
    }
    return;
  }
  __shared__ u16 smem[2 * 64 * 64];
  if (y < 16) {   // gate/up: K=NH (16 kb), N=NI (11 nb)
    int tensor = y >> 3, e = y & 7;
    const float* src = ((tensor == 0) ? gw : uw) + (size_t)e * NH * NI;
    u16* dst = ((tensor == 0) ? gT : uT) + (size_t)e * NH * NI;
    int nb = blockIdx.x % 11, kb = blockIdx.x / 11;
    transcvt_stripe(src, dst, NH, NI, kb * 64, nb * 128, smem, tid);
  } else {        // down: K=NI (22 kb), N=NH (8 nb)
    int e = y - 16;
    const float* src = dw + (size_t)e * NI * NH;
    u16* dst = dT + (size_t)e * NI * NH;
    int nb = blockIdx.x % 8, kb = blockIdx.x / 8;
    transcvt_stripe(src, dst, NI, NH, kb * 64, nb * 128, smem, tid);
  }
}

// ---------------- K2: gemm1, 128x128 tile, BK=32, 3-buf depth-2 pipeline, XCD swizzle -------
// r7 schedule (best measured) + NEW rowpair 3-bit read swizzle.
// Old 2-bit swizzle: only 4 chunk slots/row -> 8 lanes/start-bank per 16-lane phase
// (r8 measured SQ_LDS_BANK_CONFLICT 2.37M). New: slot of logical chunk (row, c) within
// rowpair rp=row>>1 is s = ((row&1)*4 + c) ^ (rp&7) -> 16 lanes hit each of the 8 b128
// start-banks exactly 2x (free, m136) -- same geometry as r0's proven 360K pattern.
// LDS stays linear (gload_lds rule #21); the permutation lives in the per-lane global src.
__global__ __launch_bounds__(256, 2) void k2_gemm1(
    const u16* __restrict__ xbf, const u16* __restrict__ gT, const u16* __restrict__ uT,
    u16* __restrict__ hbuf, const int* __restrict__ hdr, const int* __restrict__ sorted) {
  __shared__ u16 smem[36864];   // 72 KB
  int b = blockIdx.x;
  int tid = threadIdx.x;

  int job = (b & 7) * 55 + (b >> 3);   // bijective for 440 = 8*55 (XCD n-locality)
  int tile = job % 40;
  if (tile >= hdr[17]) return;
  int e = hdr[32 + tile];
  int slot0 = hdr[80 + tile];
  int n0 = (job / 40) * 128;

  const u16* aptr[2];
  const u16 *bgp[2], *bup[2];
#pragma unroll
  for (int s = 0; s < 2; ++s) {
    int idx = s * 256 + tid;           // storage chunk index
    int rp = idx >> 3, sl = idx & 7;
    int t = sl ^ (rp & 7);             // logical (row parity | k-chunk)
    int row = rp * 2 + (t >> 2);
    int c = t & 3;
    int as = sorted[slot0 + row];
    int trow = (as >= 0) ? (as >> 2) : 0;
    aptr[s] = xbf + (size_t)trow * NH + c * 8;
    size_t o = ((size_t)e * NI + n0 + row) * NH + c * 8;
    bgp[s] = gT + o; bup[s] = uT + o;
  }

  int lane = tid & 63, wave = tid >> 6;
  int wm = wave >> 1, wn = wave & 1;
  int l15 = lane & 15, quad = lane >> 4;

  f32x4 accg[4][4] = {}; f32x4 accu[4][4] = {};

#define K2_STAGE(BUF, KT)                                                \
  {                                                                      \
    int ko_ = (KT) * 32;                                                 \
    u16* p_ = smem + (BUF) * 12288;                                      \
    llds16(aptr[0] + ko_, p_ + tid * 8);                                 \
    llds16(aptr[1] + ko_, p_ + (256 + tid) * 8);                         \
    llds16(bgp[0] + ko_, p_ + 4096 + tid * 8);                           \
    llds16(bgp[1] + ko_, p_ + 4096 + (256 + tid) * 8);                   \
    llds16(bup[0] + ko_, p_ + 8192 + tid * 8);                           \
    llds16(bup[1] + ko_, p_ + 8192 + (256 + tid) * 8);                   \
  }

  K2_STAGE(0, 0);
  K2_STAGE(1, 1);
  for (int kt = 0; kt < 32; ++kt) {
    if (kt == 31) { asm volatile("s_waitcnt vmcnt(0)" ::: "memory"); }
    else          { asm volatile("s_waitcnt vmcnt(6)" ::: "memory"); }
    __builtin_amdgcn_s_barrier();
    __builtin_amdgcn_sched_barrier(0);
    if (kt < 30) K2_STAGE((kt + 2) % 3, kt + 2);
    const u16* sA  = smem + (kt % 3) * 12288;
    const u16* sBg = sA + 4096;
    const u16* sBu = sA + 8192;
    short8 av[4], bg[4], bu[4];
#pragma unroll
    for (int mf = 0; mf < 4; ++mf) {
      int r = wm * 64 + mf * 16 + l15;
      int rp = r >> 1;
      int sl = ((((r & 1) << 2) | quad) ^ (rp & 7));
      av[mf] = *(const short8*)&sA[rp * 64 + sl * 8];
    }
#pragma unroll
    for (int nf = 0; nf < 4; ++nf) {
      int r = wn * 64 + nf * 16 + l15;
      int rp = r >> 1;
      int sl = ((((r & 1) << 2) | quad) ^ (rp & 7));
      bg[nf] = *(const short8*)&sBg[rp * 64 + sl * 8];
      bu[nf] = *(const short8*)&sBu[rp * 64 + sl * 8];
    }
#pragma unroll
    for (int mf = 0; mf < 4; ++mf)
#pragma unroll
      for (int nf = 0; nf < 4; ++nf) {
        accg[mf][nf] = __builtin_amdgcn_mfma_f32_16x16x32_bf16(av[mf], bg[nf], accg[mf][nf], 0, 0, 0);
        accu[mf][nf] = __builtin_amdgcn_mfma_f32_16x16x32_bf16(av[mf], bu[nf], accu[mf][nf], 0, 0, 0);
      }
  }
#undef K2_STAGE

  for (int mf = 0; mf < 4; ++mf)
    for (int nf = 0; nf < 4; ++nf)
      for (int r = 0; r < 4; ++r) {
        int row = wm * 64 + mf * 16 + quad * 4 + r;
        int col = n0 + wn * 64 + nf * 16 + l15;
        float g2 = accg[mf][nf][r], u = accu[mf][nf][r];
        float hv = (g2 / (1.f + __expf(-g2))) * u;
        hbuf[(size_t)(slot0 + row) * NI + col] = f2b(hv);
      }
}

// ---------------- K3: down proj 128x128, BK=32, K-SPLIT-2, XCD-sliced, NO atomics ----------
// r7 schedule + rowpair 3-bit read swizzle (same fix as k2).
__global__ __launch_bounds__(256, 3) void k3_gemm2(
    const u16* __restrict__ hbuf, const u16* __restrict__ dT,
    const float* __restrict__ rw, float* __restrict__ part,
    const int* __restrict__ hdr, const int* __restrict__ sorted) {
  __shared__ u16 smem[24576];   // 48 KB
  int b = blockIdx.x;
  int nsl = b & 7;
  int r = b >> 3;
  int tile = r % 40;
  int kh = r / 40;              // 0/1: K-steps [0,22) / [22,44)
  if (tile >= hdr[17]) return;
  int e = hdr[32 + tile];
  int slot0 = hdr[80 + tile];
  int n0 = nsl * 128;
  int tid = threadIdx.x;

  const u16 *ap[2], *bp[2];
#pragma unroll
  for (int s = 0; s < 2; ++s) {
    int idx = s * 256 + tid;
    int rp = idx >> 3, sl = idx & 7;
    int t = sl ^ (rp & 7);
    int row = rp * 2 + (t >> 2);
    int c = t & 3;
    ap[s] = hbuf + (size_t)(slot0 + row) * NI + c * 8;
    bp[s] = dT + ((size_t)e * NH + n0 + row) * NI + c * 8;
  }

  int lane = tid & 63, wave = tid >> 6;
  int wm = wave >> 1, wn = wave & 1;
  int l15 = lane & 15, quad = lane >> 4;

  f32x4 acc[4][4] = {};

#define K3_STAGE(BUF, KT)                                                \
  {                                                                      \
    int ko_ = (KT) * 32;                                                 \
    u16* p_ = smem + (BUF) * 8192;                                       \
    llds16(ap[0] + ko_, p_ + tid * 8);                                   \
    llds16(ap[1] + ko_, p_ + (256 + tid) * 8);                           \
    llds16(bp[0] + ko_, p_ + 4096 + tid * 8);                            \
    llds16(bp[1] + ko_, p_ + 4096 + (256 + tid) * 8);                    \
  }

  int kt0 = kh * 22;
  K3_STAGE(0, kt0);
  K3_STAGE(1, kt0 + 1);
  for (int kt = 0; kt < 22; ++kt) {
    if (kt == 21) { asm volatile("s_waitcnt vmcnt(0)" ::: "memory"); }
    else          { asm volatile("s_waitcnt vmcnt(4)" ::: "memory"); }
    __builtin_amdgcn_s_barrier();
    __builtin_amdgcn_sched_barrier(0);
    if (kt < 20) K3_STAGE((kt + 2) % 3, kt0 + kt + 2);
    const u16* sA = smem + (kt % 3) * 8192;
    const u16* sB = sA + 4096;
    short8 av[4], bv[4];
#pragma unroll
    for (int mf = 0; mf < 4; ++mf) {
      int rr = wm * 64 + mf * 16 + l15;
      int rp = rr >> 1;
      int sl = ((((rr & 1) << 2) | quad) ^ (rp & 7));
      av[mf] = *(const short8*)&sA[rp * 64 + sl * 8];
    }
#pragma unroll
    for (int nf = 0; nf < 4; ++nf) {
      int rr = wn * 64 + nf * 16 + l15;
      int rp = rr >> 1;
      int sl = ((((rr & 1) << 2) | quad) ^ (rp & 7));
      bv[nf] = *(const short8*)&sB[rp * 64 + sl * 8];
    }
#pragma unroll
    for (int mf = 0; mf < 4; ++mf)
#pragma unroll
      for (int nf = 0; nf < 4; ++nf)
        acc[mf][nf] = __builtin_amdgcn_mfma_f32_16x16x32_bf16(av[mf], bv[nf], acc[mf][nf], 0, 0, 0);
  }
#undef K3_STAGE

  // weighted partial store into this K-half's plane (no collisions)
  float* plane = part + (size_t)kh * PART_PLANE;
  for (int mf = 0; mf < 4; ++mf) {
    int rowb = wm * 64 + mf * 16 + quad * 4;
    for (int rr = 0; rr < 4; ++rr) {
      int slot = slot0 + rowb + rr;
      int as = sorted[slot];
      if (as < 0) continue;
      float w = rw[as];
      float* prow = plane + (size_t)slot * NH + n0 + wn * 64;
      for (int nf = 0; nf < 4; ++nf)
        prow[nf * 16 + l15] = w * acc[mf][nf][rr];
    }
  }
}

// ---------------- K4: per-token combine: out[t] = sum_{k,kh} part[kh][slotOf[4t+k]] --------
__global__ __launch_bounds__(256) void k4_combine(
    const float* __restrict__ part, const int* __restrict__ slotOf,
    float* __restrict__ out) {
  int tid = threadIdx.x;
  int token = blockIdx.x * 2 + (tid >> 7);
  int col0 = (tid & 127) * 8;
  const int* sl = slotOf + token * 4;
  f4v a0 = {0.f, 0.f, 0.f, 0.f}, a1 = {0.f, 0.f, 0.f, 0.f};
#pragma unroll
  for (int k = 0; k < 4; ++k) {
    size_t ro = (size_t)sl[k] * NH + col0;
    const float* p0 = part + ro;
    const float* p1 = part + (size_t)PART_PLANE + ro;
    a0 += *(const f4v*)p0;
    a1 += *(const f4v*)(p0 + 4);
    a0 += *(const f4v*)p1;
    a1 += *(const f4v*)(p1 + 4);
  }
  float* o = out + (size_t)token * NH + col0;
  *(f4v*)o = a0;
  *(f4v*)(o + 4) = a1;
}

extern "C" void kernel_launch(void* const* d_in, const int* in_sizes, int n_in,
                              void* d_out, int out_size, void* d_ws, size_t ws_size,
                              hipStream_t stream) {
  const float* hs  = (const float*)d_in[0];
  const float* rw  = (const float*)d_in[1];
  const float* gw  = (const float*)d_in[2];
  const float* uw  = (const float*)d_in[3];
  const float* dw  = (const float*)d_in[4];
  const int*   sel = (const int*)d_in[5];
  float* out = (float*)d_out;

  char* ws = (char*)d_ws;
  int*  hdr    = (int*)(ws + WS_HDR);
  int*  sorted = (int*)(ws + WS_SORT);
  u16*  xbf    = (u16*)(ws + WS_XBF);
  u16*  gT     = (u16*)(ws + WS_GT);
  u16*  uT     = (u16*)(ws + WS_UT);
  u16*  dT     = (u16*)(ws + WS_DT);
  u16*  hb     = (u16*)(ws + WS_HB);
  float* part  = (float*)(ws + WS_GT);    // 2 planes x 21 MB in gT+uT region (dead after k2)
  int*  slotOf = (int*)(ws + WS_SLOT);    // hbuf tail rows [4992,5120)

  hipLaunchKernelGGL(k1_prep, dim3(176, 26), dim3(256), 0, stream,
                     gw, uw, dw, hs, sel, gT, uT, dT, xbf, hdr, sorted, slotOf);
  hipLaunchKernelGGL(k2_gemm1, dim3(440), dim3(256), 0, stream,
                     xbf, gT, uT, hb, hdr, sorted);
  hipLaunchKernelGGL(k3_gemm2, dim3(640), dim3(256), 0, stream,
                     hb, dT, rw, part, hdr, sorted);
  hipLaunchKernelGGL(k4_combine, dim3(512), dim3(256), 0, stream,
                     part, slotOf, out);
}